// Round 3
// baseline (518.349 us; speedup 1.0000x reference)
//
#include <hip/hip_runtime.h>

#define KSEG 10000
#define NBLK 256          // counting-sort blocks == CUs; chunk = 31250
#define HALF 5000         // bin-range phase split
#define RECMAX 17000      // LDS record capacity per phase (Binom(31250,.5): +15 sigma)
#define KITER 32          // compile-time k-loop bound: chunk <= 32768 (N <= 8.38M)
#define GBIN 3            // bins per runsort block (~35 KB LDS -> 4 blocks/CU)
#define CAPE 3072         // runsort staging capacity (3-bin mean 2400, +13 sigma)

typedef unsigned long long u64;
typedef unsigned int u32;
typedef unsigned short u16;
typedef unsigned char u8;

// ---------------- fused: hist + per-block scan + LDS-staged counting scatter ----------------
// KITER is compile-time so myd[] statically indexes -> true VGPRs (was scratch: VGPR=52).
// events folded to a per-k bitmask in pass 1 (no events re-read in scatter phases).
// flat-workgroup-size=1024 already caps VGPR at 128 (16 waves must co-reside);
// LDS 156 KB -> 1 block/CU regardless, so no min-waves hint needed.
__global__ __launch_bounds__(1024) void localsort_lds(const int* __restrict__ dur,
                                                      const float* __restrict__ log_h,
                                                      const int* __restrict__ events,
                                                      u64* __restrict__ S,
                                                      u16* __restrict__ Pb,
                                                      int N, int chunk) {
    __shared__ u64 rec[RECMAX];          // 136000 B (phase staging; overlaid by h32 early)
    __shared__ u32 cp[KSEG / 2];         // 20000 B packed dual-u16 cursors
    __shared__ u32 wsum[16];
    __shared__ u32 carry_s, pb_half;
    u32* h32 = (u32*)rec;                // 40000 B overlay, dead before rec is written

    int b = blockIdx.x;
    int s = b * chunk, e = min(N, s + chunk);
    int tid = threadIdx.x;
    int lane = tid & 63, wid = tid >> 6;

    for (int i = tid; i < KSEG; i += 1024) h32[i] = 0;
    if (tid == 0) carry_s = 0;
    __syncthreads();

    // ---- pass 1: dur -> regs, events -> bitmask, histogram ----
    int myd[KITER];
    u32 myev = 0;
#pragma unroll
    for (int k = 0; k < KITER; ++k) {
        int j = s + tid + (k << 10);
        int d = -1;
        if (j < e) {
            d = dur[j];
            myev |= (u32)(events[j] & 1) << k;
            atomicAdd(&h32[d], 1);
        }
        myd[k] = d;
    }
    __syncthreads();

    // ---- exclusive scan over KSEG bins (strips of 1024, wave-shuffle scan) ----
    for (int base = 0; base < KSEG; base += 1024) {
        int t = base + tid;
        u32 h = (t < KSEG) ? h32[t] : 0;
        u32 v = h;
        for (int off = 1; off < 64; off <<= 1) {
            u32 x = __shfl_up(v, off);
            if (lane >= off) v += x;
        }
        if (lane == 63) wsum[wid] = v;
        __syncthreads();
        if (wid == 0) {
            u32 wv = (lane < 16) ? wsum[lane] : 0;
            for (int off = 1; off < 16; off <<= 1) {
                u32 x = __shfl_up(wv, off);
                if (lane >= off) wv += x;
            }
            if (lane < 16) wsum[lane] = wv;
        }
        __syncthreads();
        u32 incl = v + ((wid > 0) ? wsum[wid - 1] : 0) + carry_s;
        u32 excl = incl - h;
        if (t < KSEG) {
            Pb[(size_t)b * (KSEG + 1) + t] = (u16)excl;
            if (!(t & 1)) cp[t >> 1] = excl | (incl << 16);  // excl_t | excl_{t+1}<<16
            if (t == HALF) pb_half = excl;                   // phase-0 element count
        }
        __syncthreads();
        if (tid == 1023) carry_s = incl;
    }
    __syncthreads();
    u32 total = carry_s;
    if (tid == 0) Pb[(size_t)b * (KSEG + 1) + KSEG] = (u16)total;
    u32 base0 = pb_half;
    __syncthreads();

    // ---- two bin-range phases: LDS scatter then coalesced dump ----
    for (int ph = 0; ph < 2; ++ph) {
        int t0 = ph ? HALF : 0;
        u32 pbase = ph ? base0 : 0;
        u32 plen = ph ? (total - base0) : base0;
#pragma unroll
        for (int k = 0; k < KITER; ++k) {
            int d = myd[k];
            if ((unsigned)(d - t0) < (unsigned)HALF) {
                int j = s + tid + (k << 10);
                u32 add = (d & 1) ? 0x10000u : 1u;
                u32 old = atomicAdd(&cp[d >> 1], add);
                u32 pos = (d & 1) ? (old >> 16) : (old & 0xffffu);
                u32 hi = ((u32)j << 1) | ((myev >> k) & 1u);
                rec[pos - pbase] = ((u64)hi << 32) | (u64)__float_as_uint(log_h[j]);
            }
        }
        __syncthreads();
        for (u32 i = tid; i < plen; i += 1024) S[(size_t)s + pbase + i] = rec[i];
        __syncthreads();
    }
}

// ---------------- counts[t] = sum_b (Pb[b][t+1]-Pb[b][t]) ----------------
__global__ void colscan_counts(const u16* __restrict__ Pb, int* __restrict__ counts) {
    int t = blockIdx.x * blockDim.x + threadIdx.x;
    if (t >= KSEG) return;
    int run = 0;
    for (int b = 0; b < NBLK; ++b) {
        const u16* row = Pb + (size_t)b * (KSEG + 1);
        run += (int)row[t + 1] - (int)row[t];
    }
    counts[t] = run;
}

// ---------------- exclusive prefix scan over K bins (single block) ----------------
__global__ void scan_kernel(const int* __restrict__ counts, int* __restrict__ cum, int K) {
    __shared__ int sm[1024];
    __shared__ int carry_s;
    int tid = threadIdx.x;
    if (tid == 0) carry_s = 0;
    __syncthreads();
    for (int base = 0; base < K; base += 1024) {
        int v = (base + tid < K) ? counts[base + tid] : 0;
        sm[tid] = v;
        __syncthreads();
        for (int off = 1; off < 1024; off <<= 1) {
            int t = (tid >= off) ? sm[tid - off] : 0;
            __syncthreads();
            sm[tid] += t;
            __syncthreads();
        }
        int carry = carry_s;
        if (base + tid < K) cum[base + tid] = carry + sm[tid] - v;  // exclusive
        __syncthreads();
        if (tid == 1023) carry_s = carry + sm[1023];
        __syncthreads();
    }
    if (tid == 0) cum[K] = carry_s;
}

// ---------------- transpose Pb[NBLK][K+1] -> PbT[K+1][NBLK] ----------------
__global__ void transpose_pb(const u16* __restrict__ Pb, u16* __restrict__ PbT) {
    __shared__ u16 tile[64][65];
    int t0 = blockIdx.x * 64;
    int b0 = blockIdx.y * 64;
    int tx = threadIdx.x;        // 0..63
    int ty = threadIdx.y;        // 0..3
    for (int r = ty; r < 64; r += 4) {
        int b = b0 + r, t = t0 + tx;
        tile[r][tx] = (b < NBLK && t <= KSEG) ? Pb[(size_t)b * (KSEG + 1) + t] : (u16)0;
    }
    __syncthreads();
    for (int r = ty; r < 64; r += 4) {
        int t = t0 + r, b = b0 + tx;
        if (t <= KSEG && b < NBLK) PbT[(size_t)t * NBLK + b] = tile[tx][r];
    }
}

// ---------------- element-parallel runsort: pid-inverted gather + batch-wide emit ----------
// GBIN=3, CAPE=3072 -> ~35 KB LDS -> 4 blocks/CU (32 waves, 100% cap).
// Phase D bin lookup is pid[x]>>8 (no linear search).
__global__ __launch_bounds__(512, 8) void runsort_ep(const u64* __restrict__ S,
                                                     const int* __restrict__ cum,
                                                     const u16* __restrict__ PbT,
                                                     float* __restrict__ P,
                                                     u32* __restrict__ J,
                                                     u32* __restrict__ E2w,
                                                     u16* __restrict__ binhint,
                                                     int N, int chunk) {
    __shared__ u64 sm[CAPE];                 // 24576 B staging
    __shared__ u16 pid[CAPE];                // 6144 B: element -> pair id
    __shared__ u16 ofs[1024];                // 2048 B: scanned run offsets (scan writes 1024)
    __shared__ u16 rows[(GBIN + 1) * 256];   // 2048 B: PbT rows (absolute per-block offsets)
    __shared__ u32 bitsSh[CAPE / 32];        // 384 B: batch-wide event bits (desc-relative)
    __shared__ u32 wpart[8];
    __shared__ int cumLoc[GBIN + 1];

    int t0 = blockIdx.x * GBIN;
    int G2 = min(GBIN, KSEG - t0);
    if (G2 <= 0) return;
    int tid = threadIdx.x;
    int lane = tid & 63, wid = tid >> 6;

    for (int i = tid; i < (G2 + 1) * 256; i += 512) {
        int t = i >> 8, b = i & 255;
        rows[i] = PbT[(size_t)(t0 + t) * NBLK + b];
    }
    if (tid <= G2) cumLoc[tid] = cum[t0 + tid];
    __syncthreads();

    int u = 0;
    while (u < G2) {
        int m = 1;
        while (u + m < G2 && cumLoc[u + m + 1] - cumLoc[u] <= CAPE) ++m;
        int aBatch = cumLoc[u];
        int tot = cumLoc[u + m] - aBatch;
        int descbase = N - cumLoc[u + m];

        // ---- run lengths (2/thread) + exclusive scan -> ofs (u16) ----
        int base2 = tid * 2;
        int l0 = 0, l1 = 0;
        {
            int tt = base2 >> 8, b = base2 & 255;
            if (tt < m) l0 = (int)rows[(u + tt + 1) * 256 + b] - (int)rows[(u + tt) * 256 + b];
            int i1 = base2 + 1;
            tt = i1 >> 8; b = i1 & 255;
            if (tt < m) l1 = (int)rows[(u + tt + 1) * 256 + b] - (int)rows[(u + tt) * 256 + b];
        }
        int sum2 = l0 + l1;
        int v = sum2;
        for (int off = 1; off < 64; off <<= 1) {
            int x = __shfl_up(v, off);
            if (lane >= off) v += x;
        }
        if (lane == 63) wpart[wid] = (u32)v;
        __syncthreads();
        if (tid == 0) {
            u32 run = 0;
            for (int w = 0; w < 8; ++w) { u32 tmp = wpart[w]; wpart[w] = run; run += tmp; }
        }
        __syncthreads();
        {
            int excl2 = v - sum2 + (int)wpart[wid];
            ofs[base2] = (u16)excl2;
            ofs[base2 + 1] = (u16)(excl2 + l0);
        }
        __syncthreads();

        // ---- phase A: pair-owner writes pid (tiny LDS writes) + zero event bits ----
        for (int i = tid; i < m * 256; i += 512) {
            int tt = i >> 8, b = i & 255;
            int l = (int)rows[(u + tt + 1) * 256 + b] - (int)rows[(u + tt) * 256 + b];
            int o = (int)ofs[i];
            for (int k = 0; k < l; ++k) pid[o + k] = (u16)i;
        }
        {
            int nw = (tot + 31) >> 5;
            for (int k = tid; k < nw; k += 512) bitsSh[k] = 0;
        }
        __syncthreads();

        // ---- phase B: element-parallel gather (independent 8B loads, high MLP) ----
        for (int x = tid; x < tot; x += 512) {
            int p = (int)pid[x];
            int tt = p >> 8, b = p & 255;
            int r0 = (int)rows[(u + tt) * 256 + b];
            int k = x - (int)ofs[p];
            sm[x] = S[(size_t)b * chunk + r0 + k];
        }
        __syncthreads();

        // ---- phase C: pair-parallel insertion sort of LDS-resident runs ----
        for (int i = tid; i < m * 256; i += 512) {
            int tt = i >> 8, b = i & 255;
            int l = (int)rows[(u + tt + 1) * 256 + b] - (int)rows[(u + tt) * 256 + b];
            int o = (int)ofs[i];
            for (int k = 1; k < l; ++k) {
                u64 key = sm[o + k];
                int jj = o + k - 1;
                while (jj >= o && sm[jj] > key) { sm[jj + 1] = sm[jj]; --jj; }
                sm[jj + 1] = key;
            }
        }
        __syncthreads();

        // ---- phase D: batch-wide emit (J coalesced; P run-coalesced; bits to LDS) ----
        for (int x = tid; x < tot; x += 512) {
            int lt = (int)pid[x] >> 8;                       // batch-local bin, no search
            u64 rec = sm[x];
            int i_in = x - (cumLoc[u + lt] - aBatch);
            int descpos = N - cumLoc[u + lt + 1] + i_in;
            P[descpos] = expf(__uint_as_float((u32)rec));
            J[aBatch + x] = (u32)(rec >> 33);
            if (rec & 0x100000000ull) {
                int bi = descpos - descbase;
                atomicOr(&bitsSh[bi >> 5], 1u << (bi & 31));
            }
        }
        // binhint for every 256-boundary inside this batch (global bin id)
        {
            int k0 = (aBatch + 255) >> 8;
            int k1e = cumLoc[u + m];
            for (int kk = k0 + tid; (kk << 8) < k1e; kk += 512) {
                int p = kk << 8;
                int lt = 0;
                while (p >= cumLoc[u + lt + 1]) ++lt;
                binhint[kk] = (u16)(t0 + u + lt);
            }
        }
        __syncthreads();

        // ---- flush event bits to global (edge words shared across blocks -> atomicOr) ----
        {
            int nw = (tot + 31) >> 5;
            for (int k = tid; k < nw; k += 512) {
                u32 vv = bitsSh[k];
                if (!vv) continue;
                long gb = (long)descbase + 32l * k;
                int w = (int)(gb >> 5), sh = (int)(gb & 31);
                atomicOr(&E2w[w], vv << sh);
                if (sh && (vv >> (32 - sh))) atomicOr(&E2w[w + 1], vv >> (32 - sh));
            }
        }
        __syncthreads();
        u += m;
    }
}

// ---------------- segment sums (faithful cross-indexing): keyed by dur[j], summand P[j] ----
__global__ __launch_bounds__(1024) void sums3(const int* __restrict__ dur,
                                              const float* __restrict__ P,
                                              const u32* __restrict__ E2w,
                                              float* __restrict__ expg_part,
                                              u16* __restrict__ evs_part,
                                              int N, int chunk) {
    __shared__ float he[KSEG];
    __shared__ int hv[KSEG];
    for (int i = threadIdx.x; i < KSEG; i += blockDim.x) { he[i] = 0.f; hv[i] = 0; }
    __syncthreads();
    int b = blockIdx.x;
    int s = b * chunk, e = min(N, s + chunk);
    for (int j = s + threadIdx.x; j < e; j += blockDim.x) {
        int t = dur[j];
        atomicAdd(&he[t], P[j]);
        if ((E2w[j >> 5] >> (j & 31)) & 1u) atomicAdd(&hv[t], 1);
    }
    __syncthreads();
    for (int i = threadIdx.x; i < KSEG; i += blockDim.x) {
        expg_part[(size_t)b * KSEG + i] = he[i];
        evs_part[(size_t)b * KSEG + i] = (u16)hv[i];
    }
}

__global__ void reduce_sums(const float* __restrict__ expg_part,
                            const u16* __restrict__ evs_part,
                            float* __restrict__ expg, float* __restrict__ evs, int B) {
    int t = blockIdx.x * blockDim.x + threadIdx.x;
    if (t >= KSEG) return;
    float a = 0.f;
    int v = 0;
    for (int b = 0; b < B; ++b) {
        a += expg_part[(size_t)b * KSEG + t];
        v += (int)evs_part[(size_t)b * KSEG + t];
    }
    expg[t] = a;
    evs[t] = (float)v;
}

// ---------------- risk suffix-sum + baseline hazard + total events ----------------
__global__ void baseline_kernel(const float* __restrict__ expg, const float* __restrict__ evs,
                                float* __restrict__ base, float* __restrict__ ev_total, int K) {
    __shared__ float sm[1024];
    __shared__ float carry_s;
    int tid = threadIdx.x;
    if (tid == 0) carry_s = 0.f;
    float evloc = 0.f;
    __syncthreads();
    for (int b = 0; b < K; b += 1024) {
        int u = b + tid;
        int t = K - 1 - u;
        float v = 0.f, ev = 0.f;
        if (u < K) { v = expg[t]; ev = evs[t]; }
        evloc += ev;
        sm[tid] = v;
        __syncthreads();
        for (int off = 1; off < 1024; off <<= 1) {
            float x = (tid >= off) ? sm[tid - off] : 0.f;
            __syncthreads();
            sm[tid] += x;
            __syncthreads();
        }
        float carry = carry_s;
        if (u < K) {
            float risk = carry + sm[tid];  // inclusive suffix sum over bins >= t
            base[t] = (risk > 0.f) ? ev / risk : 0.f;
        }
        __syncthreads();
        if (tid == 1023) carry_s = carry + sm[1023];
        __syncthreads();
    }
    sm[tid] = evloc;
    __syncthreads();
    for (int o = 512; o > 0; o >>= 1) {
        if (tid < o) sm[tid] += sm[tid + o];
        __syncthreads();
    }
    if (tid == 0) ev_total[0] = sm[0];
}

// ---------------- MSE, flat grid-stride: (base[t(i)]*P[i] - E2bit[J[i]])^2 ----------------
__global__ __launch_bounds__(1024) void mse4(const float* __restrict__ P,
                                             const u32* __restrict__ J,
                                             const u32* __restrict__ E2w,
                                             const int* __restrict__ cum,
                                             const u16* __restrict__ binhint,
                                             const float* __restrict__ base,
                                             double* __restrict__ acc, int N) {
    int stride = gridDim.x * blockDim.x;
    double s = 0.0;
    for (int i = blockIdx.x * blockDim.x + threadIdx.x; i < N; i += stride) {
        int t = (int)binhint[i >> 8];
        while (cum[t + 1] <= i) ++t;
        u32 x = J[i];
        float ev = (float)((E2w[x >> 5] >> (x & 31)) & 1u);
        float d = base[t] * P[i] - ev;
        s += (double)d * (double)d;
    }
    __shared__ double sm[1024];
    sm[threadIdx.x] = s;
    __syncthreads();
    for (int o = 512; o > 0; o >>= 1) {
        if ((int)threadIdx.x < o) sm[threadIdx.x] += sm[threadIdx.x + o];
        __syncthreads();
    }
    if (threadIdx.x == 0) atomicAdd(acc, sm[0]);
}

__global__ void final_kernel(const double* __restrict__ acc, const float* __restrict__ ev_total,
                             float* __restrict__ out, int N) {
    out[0] = (ev_total[0] == 0.f) ? 0.0f : (float)(*acc / (double)N);
}

extern "C" void kernel_launch(void* const* d_in, const int* in_sizes, int n_in,
                              void* d_out, int out_size, void* d_ws, size_t ws_size,
                              hipStream_t stream) {
    const float* log_h = (const float*)d_in[0];
    const int* dur     = (const int*)d_in[1];
    const int* events  = (const int*)d_in[2];
    int N = in_sizes[0];
    float* out = (float*)d_out;

    char* ws = (char*)d_ws;
    size_t off = 0;
    auto alloc = [&](size_t bytes) -> char* {
        char* p = ws + off;
        off = (off + bytes + 255) & ~(size_t)255;
        return p;
    };
    double* acc  = (double*)alloc(8);
    u32*    E2w  = (u32*)alloc(((size_t)N / 32 + 2) * 4);   // event bitfield (desc-indexed)
    size_t zero_bytes = off;                                 // acc + E2w must start at 0
    float*  ev_total = (float*)alloc(4);
    int*    counts   = (int*)alloc(KSEG * 4);
    int*    cum      = (int*)alloc((KSEG + 1) * 4);
    float*  expg     = (float*)alloc(KSEG * 4);
    float*  evs      = (float*)alloc(KSEG * 4);
    float*  base     = (float*)alloc(KSEG * 4);
    u16*    binhint  = (u16*)alloc(((size_t)N / 256 + 1) * 2);
    u16*    Pb       = (u16*)alloc((size_t)NBLK * (KSEG + 1) * 2);
    u16*    PbT      = (u16*)alloc((size_t)(KSEG + 1) * NBLK * 2);
    u64*    S        = (u64*)alloc((size_t)N * 8);
    float*  P        = (float*)alloc((size_t)N * 4);
    u32*    J        = (u32*)alloc((size_t)N * 4);
    (void)ws_size;

    // sums partials alias S (dead after runsort_ep; mse4 uses P/J, not S)
    float* expg_part = (float*)S;
    u16*   evs_part  = (u16*)((char*)S + (size_t)NBLK * KSEG * 4 + 256);

    int chunk = (N + NBLK - 1) / NBLK;   // 31250 < 65536 -> u16 offsets valid

    hipMemsetAsync(d_ws, 0, zero_bytes, stream);

    localsort_lds<<<NBLK, 1024, 0, stream>>>(dur, log_h, events, S, Pb, N, chunk);
    colscan_counts<<<(KSEG + 255) / 256, 256, 0, stream>>>(Pb, counts);
    scan_kernel<<<1, 1024, 0, stream>>>(counts, cum, KSEG);
    transpose_pb<<<dim3((KSEG + 64) / 64, NBLK / 64), dim3(64, 4), 0, stream>>>(Pb, PbT);
    runsort_ep<<<(KSEG + GBIN - 1) / GBIN, 512, 0, stream>>>(S, cum, PbT, P, J, E2w,
                                                             binhint, N, chunk);
    sums3<<<NBLK, 1024, 0, stream>>>(dur, P, E2w, expg_part, evs_part, N, chunk);
    reduce_sums<<<(KSEG + 255) / 256, 256, 0, stream>>>(expg_part, evs_part, expg, evs, NBLK);
    baseline_kernel<<<1, 1024, 0, stream>>>(expg, evs, base, ev_total, KSEG);
    mse4<<<512, 1024, 0, stream>>>(P, J, E2w, cum, binhint, base, acc, N);
    final_kernel<<<1, 1, 0, stream>>>(acc, ev_total, out, N);
}

// Round 4
// 463.872 us; speedup vs baseline: 1.1174x; 1.1174x over previous
//
#include <hip/hip_runtime.h>

#define KSEG 10000
#define NBLK 256          // counting-sort blocks == CUs; chunk = 31250
#define HALF 5000         // bin-range phase split
#define RECMAX 17000      // LDS record capacity per phase (Binom(31250,.5): +15 sigma)
#define GBIN 3            // bins per runsort block (~35 KB LDS -> 4 blocks/CU)
#define CAPE 3072         // runsort staging capacity (3-bin mean 2400, +13 sigma)

typedef unsigned long long u64;
typedef unsigned int u32;
typedef unsigned short u16;
typedef unsigned char u8;

// ---------------- fused: hist + per-block scan + LDS-staged counting scatter ----------------
// No per-thread dur array (R3 lesson: spill leaked 113 MB scratch to HBM). dur is re-read
// per scatter phase: each block's 125 KB chunk is L1/L2-resident on re-read. events folded
// into a 1-bit-per-k register bitmask in pass 1 (kiter <= 31 < 32 for chunk = 31250).
__global__ __launch_bounds__(1024) void localsort_lds(const int* __restrict__ dur,
                                                      const float* __restrict__ log_h,
                                                      const int* __restrict__ events,
                                                      u64* __restrict__ S,
                                                      u16* __restrict__ Pb,
                                                      int N, int chunk) {
    __shared__ u64 rec[RECMAX];          // 136000 B (phase staging; overlaid by h32 early)
    __shared__ u32 cp[KSEG / 2];         // 20000 B packed dual-u16 cursors
    __shared__ u32 wsum[16];
    __shared__ u32 carry_s, pb_half;
    u32* h32 = (u32*)rec;                // 40000 B overlay, dead before rec is written

    int b = blockIdx.x;
    int s = b * chunk, e = min(N, s + chunk);
    int tid = threadIdx.x;
    int lane = tid & 63, wid = tid >> 6;
    int kiter = (chunk + 1023) >> 10;    // 31 for N=8M

    for (int i = tid; i < KSEG; i += 1024) h32[i] = 0;
    if (tid == 0) carry_s = 0;
    __syncthreads();

    // ---- pass 1: histogram; events -> register bitmask ----
    u32 myev = 0;
    for (int k = 0; k < kiter; ++k) {
        int j = s + tid + (k << 10);
        if (j < e) {
            int d = dur[j];
            myev |= (u32)(events[j] & 1) << k;
            atomicAdd(&h32[d], 1);
        }
    }
    __syncthreads();

    // ---- exclusive scan over KSEG bins (strips of 1024, wave-shuffle scan) ----
    for (int base = 0; base < KSEG; base += 1024) {
        int t = base + tid;
        u32 h = (t < KSEG) ? h32[t] : 0;
        u32 v = h;
        for (int off = 1; off < 64; off <<= 1) {
            u32 x = __shfl_up(v, off);
            if (lane >= off) v += x;
        }
        if (lane == 63) wsum[wid] = v;
        __syncthreads();
        if (wid == 0) {
            u32 wv = (lane < 16) ? wsum[lane] : 0;
            for (int off = 1; off < 16; off <<= 1) {
                u32 x = __shfl_up(wv, off);
                if (lane >= off) wv += x;
            }
            if (lane < 16) wsum[lane] = wv;
        }
        __syncthreads();
        u32 incl = v + ((wid > 0) ? wsum[wid - 1] : 0) + carry_s;
        u32 excl = incl - h;
        if (t < KSEG) {
            Pb[(size_t)b * (KSEG + 1) + t] = (u16)excl;
            if (!(t & 1)) cp[t >> 1] = excl | (incl << 16);  // excl_t | excl_{t+1}<<16
            if (t == HALF) pb_half = excl;                   // phase-0 element count
        }
        __syncthreads();
        if (tid == 1023) carry_s = incl;
    }
    __syncthreads();
    u32 total = carry_s;
    if (tid == 0) Pb[(size_t)b * (KSEG + 1) + KSEG] = (u16)total;
    u32 base0 = pb_half;
    __syncthreads();

    // ---- two bin-range phases: LDS scatter then coalesced dump (dur re-read, L2-warm) ----
    for (int ph = 0; ph < 2; ++ph) {
        int t0 = ph ? HALF : 0;
        u32 pbase = ph ? base0 : 0;
        u32 plen = ph ? (total - base0) : base0;
        for (int k = 0; k < kiter; ++k) {
            int j = s + tid + (k << 10);
            if (j < e) {
                int d = dur[j];
                if ((unsigned)(d - t0) < (unsigned)HALF) {
                    u32 add = (d & 1) ? 0x10000u : 1u;
                    u32 old = atomicAdd(&cp[d >> 1], add);
                    u32 pos = (d & 1) ? (old >> 16) : (old & 0xffffu);
                    u32 hi = ((u32)j << 1) | ((myev >> k) & 1u);
                    rec[pos - pbase] = ((u64)hi << 32) | (u64)__float_as_uint(log_h[j]);
                }
            }
        }
        __syncthreads();
        for (u32 i = tid; i < plen; i += 1024) S[(size_t)s + pbase + i] = rec[i];
        __syncthreads();
    }
}

// ---------------- counts[t] = sum_b (Pb[b][t+1]-Pb[b][t]) ----------------
__global__ void colscan_counts(const u16* __restrict__ Pb, int* __restrict__ counts) {
    int t = blockIdx.x * blockDim.x + threadIdx.x;
    if (t >= KSEG) return;
    int run = 0;
    for (int b = 0; b < NBLK; ++b) {
        const u16* row = Pb + (size_t)b * (KSEG + 1);
        run += (int)row[t + 1] - (int)row[t];
    }
    counts[t] = run;
}

// ---------------- exclusive prefix scan over K bins (single block, wave-shuffle) ----------
__global__ __launch_bounds__(1024) void scan_kernel(const int* __restrict__ counts,
                                                    int* __restrict__ cum, int K) {
    __shared__ int wsum[16];
    __shared__ int carry_s;
    int tid = threadIdx.x, lane = tid & 63, wid = tid >> 6;
    if (tid == 0) carry_s = 0;
    __syncthreads();
    for (int base = 0; base < K; base += 1024) {
        int t = base + tid;
        int h = (t < K) ? counts[t] : 0;
        int v = h;
        for (int off = 1; off < 64; off <<= 1) {
            int x = __shfl_up(v, off);
            if (lane >= off) v += x;
        }
        if (lane == 63) wsum[wid] = v;
        __syncthreads();
        if (wid == 0) {
            int wv = (lane < 16) ? wsum[lane] : 0;
            for (int off = 1; off < 16; off <<= 1) {
                int x = __shfl_up(wv, off);
                if (lane >= off) wv += x;
            }
            if (lane < 16) wsum[lane] = wv;
        }
        __syncthreads();
        int incl = v + ((wid > 0) ? wsum[wid - 1] : 0) + carry_s;
        if (t < K) cum[t] = incl - h;  // exclusive
        __syncthreads();
        if (tid == 1023) carry_s = incl;
    }
    __syncthreads();
    if (tid == 0) cum[K] = carry_s;
}

// ---------------- transpose Pb[NBLK][K+1] -> PbT[K+1][NBLK] ----------------
__global__ void transpose_pb(const u16* __restrict__ Pb, u16* __restrict__ PbT) {
    __shared__ u16 tile[64][65];
    int t0 = blockIdx.x * 64;
    int b0 = blockIdx.y * 64;
    int tx = threadIdx.x;        // 0..63
    int ty = threadIdx.y;        // 0..3
    for (int r = ty; r < 64; r += 4) {
        int b = b0 + r, t = t0 + tx;
        tile[r][tx] = (b < NBLK && t <= KSEG) ? Pb[(size_t)b * (KSEG + 1) + t] : (u16)0;
    }
    __syncthreads();
    for (int r = ty; r < 64; r += 4) {
        int t = t0 + r, b = b0 + tx;
        if (t <= KSEG && b < NBLK) PbT[(size_t)t * NBLK + b] = tile[tx][r];
    }
}

// ---------------- element-parallel runsort: pid-inverted gather + batch-wide emit ----------
// GBIN=3, CAPE=3072 -> ~35 KB LDS -> 4 blocks/CU (32 waves, 100% cap).
// Phase D bin lookup is pid[x]>>8 (no linear search).
__global__ __launch_bounds__(512, 8) void runsort_ep(const u64* __restrict__ S,
                                                     const int* __restrict__ cum,
                                                     const u16* __restrict__ PbT,
                                                     float* __restrict__ P,
                                                     u32* __restrict__ J,
                                                     u32* __restrict__ E2w,
                                                     u16* __restrict__ binhint,
                                                     int N, int chunk) {
    __shared__ u64 sm[CAPE];                 // 24576 B staging
    __shared__ u16 pid[CAPE];                // 6144 B: element -> pair id
    __shared__ u16 ofs[1024];                // 2048 B: scanned run offsets (scan writes 1024)
    __shared__ u16 rows[(GBIN + 1) * 256];   // 2048 B: PbT rows (absolute per-block offsets)
    __shared__ u32 bitsSh[CAPE / 32];        // 384 B: batch-wide event bits (desc-relative)
    __shared__ u32 wpart[8];
    __shared__ int cumLoc[GBIN + 1];

    int t0 = blockIdx.x * GBIN;
    int G2 = min(GBIN, KSEG - t0);
    if (G2 <= 0) return;
    int tid = threadIdx.x;
    int lane = tid & 63, wid = tid >> 6;

    for (int i = tid; i < (G2 + 1) * 256; i += 512) {
        int t = i >> 8, b = i & 255;
        rows[i] = PbT[(size_t)(t0 + t) * NBLK + b];
    }
    if (tid <= G2) cumLoc[tid] = cum[t0 + tid];
    __syncthreads();

    int u = 0;
    while (u < G2) {
        int m = 1;
        while (u + m < G2 && cumLoc[u + m + 1] - cumLoc[u] <= CAPE) ++m;
        int aBatch = cumLoc[u];
        int tot = cumLoc[u + m] - aBatch;
        int descbase = N - cumLoc[u + m];

        // ---- run lengths (2/thread) + exclusive scan -> ofs (u16) ----
        int base2 = tid * 2;
        int l0 = 0, l1 = 0;
        {
            int tt = base2 >> 8, b = base2 & 255;
            if (tt < m) l0 = (int)rows[(u + tt + 1) * 256 + b] - (int)rows[(u + tt) * 256 + b];
            int i1 = base2 + 1;
            tt = i1 >> 8; b = i1 & 255;
            if (tt < m) l1 = (int)rows[(u + tt + 1) * 256 + b] - (int)rows[(u + tt) * 256 + b];
        }
        int sum2 = l0 + l1;
        int v = sum2;
        for (int off = 1; off < 64; off <<= 1) {
            int x = __shfl_up(v, off);
            if (lane >= off) v += x;
        }
        if (lane == 63) wpart[wid] = (u32)v;
        __syncthreads();
        if (tid == 0) {
            u32 run = 0;
            for (int w = 0; w < 8; ++w) { u32 tmp = wpart[w]; wpart[w] = run; run += tmp; }
        }
        __syncthreads();
        {
            int excl2 = v - sum2 + (int)wpart[wid];
            ofs[base2] = (u16)excl2;
            ofs[base2 + 1] = (u16)(excl2 + l0);
        }
        __syncthreads();

        // ---- phase A: pair-owner writes pid (tiny LDS writes) + zero event bits ----
        for (int i = tid; i < m * 256; i += 512) {
            int tt = i >> 8, b = i & 255;
            int l = (int)rows[(u + tt + 1) * 256 + b] - (int)rows[(u + tt) * 256 + b];
            int o = (int)ofs[i];
            for (int k = 0; k < l; ++k) pid[o + k] = (u16)i;
        }
        {
            int nw = (tot + 31) >> 5;
            for (int k = tid; k < nw; k += 512) bitsSh[k] = 0;
        }
        __syncthreads();

        // ---- phase B: element-parallel gather (independent 8B loads, high MLP) ----
        for (int x = tid; x < tot; x += 512) {
            int p = (int)pid[x];
            int tt = p >> 8, b = p & 255;
            int r0 = (int)rows[(u + tt) * 256 + b];
            int k = x - (int)ofs[p];
            sm[x] = S[(size_t)b * chunk + r0 + k];
        }
        __syncthreads();

        // ---- phase C: pair-parallel insertion sort of LDS-resident runs ----
        for (int i = tid; i < m * 256; i += 512) {
            int tt = i >> 8, b = i & 255;
            int l = (int)rows[(u + tt + 1) * 256 + b] - (int)rows[(u + tt) * 256 + b];
            int o = (int)ofs[i];
            for (int k = 1; k < l; ++k) {
                u64 key = sm[o + k];
                int jj = o + k - 1;
                while (jj >= o && sm[jj] > key) { sm[jj + 1] = sm[jj]; --jj; }
                sm[jj + 1] = key;
            }
        }
        __syncthreads();

        // ---- phase D: batch-wide emit (J coalesced; P run-coalesced; bits to LDS) ----
        for (int x = tid; x < tot; x += 512) {
            int lt = (int)pid[x] >> 8;                       // batch-local bin, no search
            u64 rec = sm[x];
            int i_in = x - (cumLoc[u + lt] - aBatch);
            int descpos = N - cumLoc[u + lt + 1] + i_in;
            P[descpos] = expf(__uint_as_float((u32)rec));
            J[aBatch + x] = (u32)(rec >> 33);
            if (rec & 0x100000000ull) {
                int bi = descpos - descbase;
                atomicOr(&bitsSh[bi >> 5], 1u << (bi & 31));
            }
        }
        // binhint for every 256-boundary inside this batch (global bin id)
        {
            int k0 = (aBatch + 255) >> 8;
            int k1e = cumLoc[u + m];
            for (int kk = k0 + tid; (kk << 8) < k1e; kk += 512) {
                int p = kk << 8;
                int lt = 0;
                while (p >= cumLoc[u + lt + 1]) ++lt;
                binhint[kk] = (u16)(t0 + u + lt);
            }
        }
        __syncthreads();

        // ---- flush event bits to global (edge words shared across blocks -> atomicOr) ----
        {
            int nw = (tot + 31) >> 5;
            for (int k = tid; k < nw; k += 512) {
                u32 vv = bitsSh[k];
                if (!vv) continue;
                long gb = (long)descbase + 32l * k;
                int w = (int)(gb >> 5), sh = (int)(gb & 31);
                atomicOr(&E2w[w], vv << sh);
                if (sh && (vv >> (32 - sh))) atomicOr(&E2w[w + 1], vv >> (32 - sh));
            }
        }
        __syncthreads();
        u += m;
    }
}

// ---------------- segment sums (faithful cross-indexing): keyed by dur[j], summand P[j] ----
__global__ __launch_bounds__(1024) void sums3(const int* __restrict__ dur,
                                              const float* __restrict__ P,
                                              const u32* __restrict__ E2w,
                                              float* __restrict__ expg_part,
                                              u16* __restrict__ evs_part,
                                              int N, int chunk) {
    __shared__ float he[KSEG];
    __shared__ int hv[KSEG];
    for (int i = threadIdx.x; i < KSEG; i += blockDim.x) { he[i] = 0.f; hv[i] = 0; }
    __syncthreads();
    int b = blockIdx.x;
    int s = b * chunk, e = min(N, s + chunk);
    for (int j = s + threadIdx.x; j < e; j += blockDim.x) {
        int t = dur[j];
        atomicAdd(&he[t], P[j]);
        if ((E2w[j >> 5] >> (j & 31)) & 1u) atomicAdd(&hv[t], 1);
    }
    __syncthreads();
    for (int i = threadIdx.x; i < KSEG; i += blockDim.x) {
        expg_part[(size_t)b * KSEG + i] = he[i];
        evs_part[(size_t)b * KSEG + i] = (u16)hv[i];
    }
}

__global__ void reduce_sums(const float* __restrict__ expg_part,
                            const u16* __restrict__ evs_part,
                            float* __restrict__ expg, float* __restrict__ evs, int B) {
    int t = blockIdx.x * blockDim.x + threadIdx.x;
    if (t >= KSEG) return;
    float a = 0.f;
    int v = 0;
    for (int b = 0; b < B; ++b) {
        a += expg_part[(size_t)b * KSEG + t];
        v += (int)evs_part[(size_t)b * KSEG + t];
    }
    expg[t] = a;
    evs[t] = (float)v;
}

// ---------------- risk suffix-sum + baseline hazard + total events (wave-shuffle) --------
__global__ __launch_bounds__(1024) void baseline_kernel(const float* __restrict__ expg,
                                                        const float* __restrict__ evs,
                                                        float* __restrict__ base,
                                                        float* __restrict__ ev_total, int K) {
    __shared__ float fwsum[16];
    __shared__ float carry_s;
    int tid = threadIdx.x, lane = tid & 63, wid = tid >> 6;
    if (tid == 0) carry_s = 0.f;
    float evloc = 0.f;
    __syncthreads();
    for (int b = 0; b < K; b += 1024) {
        int u = b + tid;
        int t = K - 1 - u;
        float h = 0.f, ev = 0.f;
        if (u < K) { h = expg[t]; ev = evs[t]; }
        evloc += ev;
        float v = h;
        for (int off = 1; off < 64; off <<= 1) {
            float x = __shfl_up(v, off);
            if (lane >= off) v += x;
        }
        if (lane == 63) fwsum[wid] = v;
        __syncthreads();
        if (wid == 0) {
            float wv = (lane < 16) ? fwsum[lane] : 0.f;
            for (int off = 1; off < 16; off <<= 1) {
                float x = __shfl_up(wv, off);
                if (lane >= off) wv += x;
            }
            if (lane < 16) fwsum[lane] = wv;
        }
        __syncthreads();
        float risk = v + ((wid > 0) ? fwsum[wid - 1] : 0.f) + carry_s;  // inclusive suffix
        if (u < K) base[t] = (risk > 0.f) ? ev / risk : 0.f;
        __syncthreads();
        if (tid == 1023) carry_s = risk;
    }
    // total events: wave reduce + cross-wave
    for (int off = 32; off > 0; off >>= 1) evloc += __shfl_down(evloc, off);
    __syncthreads();
    if (lane == 0) fwsum[wid] = evloc;
    __syncthreads();
    if (tid == 0) {
        float st = 0.f;
        for (int w = 0; w < 16; ++w) st += fwsum[w];
        ev_total[0] = st;
    }
}

// ---------------- MSE, flat grid-stride: (base[t(i)]*P[i] - E2bit[J[i]])^2 ----------------
__global__ __launch_bounds__(1024) void mse4(const float* __restrict__ P,
                                             const u32* __restrict__ J,
                                             const u32* __restrict__ E2w,
                                             const int* __restrict__ cum,
                                             const u16* __restrict__ binhint,
                                             const float* __restrict__ base,
                                             double* __restrict__ acc, int N) {
    int stride = gridDim.x * blockDim.x;
    double s = 0.0;
    for (int i = blockIdx.x * blockDim.x + threadIdx.x; i < N; i += stride) {
        int t = (int)binhint[i >> 8];
        while (cum[t + 1] <= i) ++t;
        u32 x = J[i];
        float ev = (float)((E2w[x >> 5] >> (x & 31)) & 1u);
        float d = base[t] * P[i] - ev;
        s += (double)d * (double)d;
    }
    __shared__ double sm[1024];
    sm[threadIdx.x] = s;
    __syncthreads();
    for (int o = 512; o > 0; o >>= 1) {
        if ((int)threadIdx.x < o) sm[threadIdx.x] += sm[threadIdx.x + o];
        __syncthreads();
    }
    if (threadIdx.x == 0) atomicAdd(acc, sm[0]);
}

__global__ void final_kernel(const double* __restrict__ acc, const float* __restrict__ ev_total,
                             float* __restrict__ out, int N) {
    out[0] = (ev_total[0] == 0.f) ? 0.0f : (float)(*acc / (double)N);
}

extern "C" void kernel_launch(void* const* d_in, const int* in_sizes, int n_in,
                              void* d_out, int out_size, void* d_ws, size_t ws_size,
                              hipStream_t stream) {
    const float* log_h = (const float*)d_in[0];
    const int* dur     = (const int*)d_in[1];
    const int* events  = (const int*)d_in[2];
    int N = in_sizes[0];
    float* out = (float*)d_out;

    char* ws = (char*)d_ws;
    size_t off = 0;
    auto alloc = [&](size_t bytes) -> char* {
        char* p = ws + off;
        off = (off + bytes + 255) & ~(size_t)255;
        return p;
    };
    double* acc  = (double*)alloc(8);
    u32*    E2w  = (u32*)alloc(((size_t)N / 32 + 2) * 4);   // event bitfield (desc-indexed)
    size_t zero_bytes = off;                                 // acc + E2w must start at 0
    float*  ev_total = (float*)alloc(4);
    int*    counts   = (int*)alloc(KSEG * 4);
    int*    cum      = (int*)alloc((KSEG + 1) * 4);
    float*  expg     = (float*)alloc(KSEG * 4);
    float*  evs      = (float*)alloc(KSEG * 4);
    float*  base     = (float*)alloc(KSEG * 4);
    u16*    binhint  = (u16*)alloc(((size_t)N / 256 + 1) * 2);
    u16*    Pb       = (u16*)alloc((size_t)NBLK * (KSEG + 1) * 2);
    u16*    PbT      = (u16*)alloc((size_t)(KSEG + 1) * NBLK * 2);
    u64*    S        = (u64*)alloc((size_t)N * 8);
    float*  P        = (float*)alloc((size_t)N * 4);
    u32*    J        = (u32*)alloc((size_t)N * 4);
    (void)ws_size;

    // sums partials alias S (dead after runsort_ep; mse4 uses P/J, not S)
    float* expg_part = (float*)S;
    u16*   evs_part  = (u16*)((char*)S + (size_t)NBLK * KSEG * 4 + 256);

    int chunk = (N + NBLK - 1) / NBLK;   // 31250 < 65536 -> u16 offsets valid

    hipMemsetAsync(d_ws, 0, zero_bytes, stream);

    localsort_lds<<<NBLK, 1024, 0, stream>>>(dur, log_h, events, S, Pb, N, chunk);
    colscan_counts<<<(KSEG + 255) / 256, 256, 0, stream>>>(Pb, counts);
    scan_kernel<<<1, 1024, 0, stream>>>(counts, cum, KSEG);
    transpose_pb<<<dim3((KSEG + 64) / 64, NBLK / 64), dim3(64, 4), 0, stream>>>(Pb, PbT);
    runsort_ep<<<(KSEG + GBIN - 1) / GBIN, 512, 0, stream>>>(S, cum, PbT, P, J, E2w,
                                                             binhint, N, chunk);
    sums3<<<NBLK, 1024, 0, stream>>>(dur, P, E2w, expg_part, evs_part, N, chunk);
    reduce_sums<<<(KSEG + 255) / 256, 256, 0, stream>>>(expg_part, evs_part, expg, evs, NBLK);
    baseline_kernel<<<1, 1024, 0, stream>>>(expg, evs, base, ev_total, KSEG);
    mse4<<<512, 1024, 0, stream>>>(P, J, E2w, cum, binhint, base, acc, N);
    final_kernel<<<1, 1, 0, stream>>>(acc, ev_total, out, N);
}

// Round 5
// 442.207 us; speedup vs baseline: 1.1722x; 1.0490x over previous
//
#include <hip/hip_runtime.h>

#define KSEG 10000
#define NBLK 256          // counting-sort blocks == CUs; chunk = 31250
#define RECN 32768        // one-phase u32 record capacity (chunk <= 32768)
#define GBIN 3            // bins per runsort block (~35 KB LDS -> 4 blocks/CU)
#define CAPE 3072         // runsort staging capacity (3-bin mean 2400, +13 sigma)

typedef unsigned long long u64;
typedef unsigned int u32;
typedef unsigned short u16;
typedef unsigned char u8;

// ---------------- fused: hist + per-block scan + ONE-phase LDS counting scatter ----------
// u32 records (local_j<<1|ev) let the whole 31250-element chunk stage in LDS at once:
// 128 KB rec32 + 20 KB cursors = ~148 KB. Dump reconstructs u64 S records, gathering
// log_h from the block's own 125 KB window (L2-resident). One dur pass fewer than R4.
__global__ __launch_bounds__(1024) void localsort_lds(const int* __restrict__ dur,
                                                      const float* __restrict__ log_h,
                                                      const int* __restrict__ events,
                                                      u64* __restrict__ S,
                                                      u16* __restrict__ Pb,
                                                      int N, int chunk) {
    __shared__ u32 rec32[RECN];          // 131072 B (h32 overlays first 40000 B)
    __shared__ u32 cp[KSEG / 2];         // 20000 B packed dual-u16 cursors
    __shared__ u32 wsum[16];
    __shared__ u32 carry_s;
    u32* h32 = rec32;                    // histogram overlay, dead before rec32 is written

    int b = blockIdx.x;
    int s = b * chunk, e = min(N, s + chunk);
    int tid = threadIdx.x;
    int lane = tid & 63, wid = tid >> 6;
    int kiter = (chunk + 1023) >> 10;    // 31 for N=8M (<=32 so myev bitmask fits u32)

    for (int i = tid; i < KSEG; i += 1024) h32[i] = 0;
    if (tid == 0) carry_s = 0;
    __syncthreads();

    // ---- pass 1: histogram; events -> register bitmask ----
    u32 myev = 0;
    for (int k = 0; k < kiter; ++k) {
        int j = s + tid + (k << 10);
        if (j < e) {
            int d = dur[j];
            myev |= (u32)(events[j] & 1) << k;
            atomicAdd(&h32[d], 1);
        }
    }
    __syncthreads();

    // ---- exclusive scan over KSEG bins (strips of 1024, wave-shuffle scan) ----
    for (int base = 0; base < KSEG; base += 1024) {
        int t = base + tid;
        u32 h = (t < KSEG) ? h32[t] : 0;
        u32 v = h;
        for (int off = 1; off < 64; off <<= 1) {
            u32 x = __shfl_up(v, off);
            if (lane >= off) v += x;
        }
        if (lane == 63) wsum[wid] = v;
        __syncthreads();
        if (wid == 0) {
            u32 wv = (lane < 16) ? wsum[lane] : 0;
            for (int off = 1; off < 16; off <<= 1) {
                u32 x = __shfl_up(wv, off);
                if (lane >= off) wv += x;
            }
            if (lane < 16) wsum[lane] = wv;
        }
        __syncthreads();
        u32 incl = v + ((wid > 0) ? wsum[wid - 1] : 0) + carry_s;
        u32 excl = incl - h;
        if (t < KSEG) {
            Pb[(size_t)b * (KSEG + 1) + t] = (u16)excl;
            if (!(t & 1)) cp[t >> 1] = excl | (incl << 16);  // excl_t | excl_{t+1}<<16
        }
        __syncthreads();
        if (tid == 1023) carry_s = incl;
    }
    __syncthreads();
    u32 total = carry_s;
    if (tid == 0) Pb[(size_t)b * (KSEG + 1) + KSEG] = (u16)total;
    __syncthreads();

    // ---- single scatter phase: all bins into rec32 (dur re-read once, L2-warm) ----
    for (int k = 0; k < kiter; ++k) {
        int j = s + tid + (k << 10);
        if (j < e) {
            int d = dur[j];
            u32 add = (d & 1) ? 0x10000u : 1u;
            u32 old = atomicAdd(&cp[d >> 1], add);
            u32 pos = (d & 1) ? (old >> 16) : (old & 0xffffu);
            rec32[pos] = ((u32)(tid + (k << 10)) << 1) | ((myev >> k) & 1u);
        }
    }
    __syncthreads();

    // ---- coalesced dump: reconstruct u64 records; log_h gather stays in block window ----
    for (u32 i = tid; i < total; i += 1024) {
        u32 v = rec32[i];
        int j = s + (int)(v >> 1);
        u32 hi = ((u32)j << 1) | (v & 1u);
        S[(size_t)s + i] = ((u64)hi << 32) | (u64)__float_as_uint(log_h[j]);
    }
}

// ---------------- transpose Pb[NBLK][K+1] -> PbT[K+1][NBLK] ----------------
__global__ void transpose_pb(const u16* __restrict__ Pb, u16* __restrict__ PbT) {
    __shared__ u16 tile[64][65];
    int t0 = blockIdx.x * 64;
    int b0 = blockIdx.y * 64;
    int tx = threadIdx.x;        // 0..63
    int ty = threadIdx.y;        // 0..3
    for (int r = ty; r < 64; r += 4) {
        int b = b0 + r, t = t0 + tx;
        tile[r][tx] = (b < NBLK && t <= KSEG) ? Pb[(size_t)b * (KSEG + 1) + t] : (u16)0;
    }
    __syncthreads();
    for (int r = ty; r < 64; r += 4) {
        int t = t0 + r, b = b0 + tx;
        if (t <= KSEG && b < NBLK) PbT[(size_t)t * NBLK + b] = tile[tx][r];
    }
}

// ---------------- cum[t] = sum_b Pb[b][t] (sum of per-block EXCLUSIVE prefixes IS the
// global exclusive prefix -> colscan_counts + scan_kernel are algebraically redundant).
// One wave per PbT row (512 B contiguous), shuffle-reduce. ----------------
__global__ __launch_bounds__(256) void cum_rows(const u16* __restrict__ PbT,
                                                int* __restrict__ cum) {
    int r = blockIdx.x * 4 + (threadIdx.x >> 6);
    if (r > KSEG) return;
    int lane = threadIdx.x & 63;
    const ushort4* row = (const ushort4*)(PbT + (size_t)r * NBLK);
    ushort4 v = row[lane];
    int sum = (int)v.x + (int)v.y + (int)v.z + (int)v.w;
    for (int off = 32; off > 0; off >>= 1) sum += __shfl_down(sum, off);
    if (lane == 0) cum[r] = sum;
}

// ---------------- element-parallel runsort: pid-inverted gather + batch-wide emit ----------
// GBIN=3, CAPE=3072 -> ~35 KB LDS -> 4 blocks/CU (32 waves, 100% cap).
// Phase D bin lookup is pid[x]>>8 (no linear search).
__global__ __launch_bounds__(512, 8) void runsort_ep(const u64* __restrict__ S,
                                                     const int* __restrict__ cum,
                                                     const u16* __restrict__ PbT,
                                                     float* __restrict__ P,
                                                     u32* __restrict__ J,
                                                     u32* __restrict__ E2w,
                                                     u16* __restrict__ binhint,
                                                     int N, int chunk) {
    __shared__ u64 sm[CAPE];                 // 24576 B staging
    __shared__ u16 pid[CAPE];                // 6144 B: element -> pair id
    __shared__ u16 ofs[1024];                // 2048 B: scanned run offsets (scan writes 1024)
    __shared__ u16 rows[(GBIN + 1) * 256];   // 2048 B: PbT rows (absolute per-block offsets)
    __shared__ u32 bitsSh[CAPE / 32];        // 384 B: batch-wide event bits (desc-relative)
    __shared__ u32 wpart[8];
    __shared__ int cumLoc[GBIN + 1];

    int t0 = blockIdx.x * GBIN;
    int G2 = min(GBIN, KSEG - t0);
    if (G2 <= 0) return;
    int tid = threadIdx.x;
    int lane = tid & 63, wid = tid >> 6;

    for (int i = tid; i < (G2 + 1) * 256; i += 512) {
        int t = i >> 8, b = i & 255;
        rows[i] = PbT[(size_t)(t0 + t) * NBLK + b];
    }
    if (tid <= G2) cumLoc[tid] = cum[t0 + tid];
    __syncthreads();

    int u = 0;
    while (u < G2) {
        int m = 1;
        while (u + m < G2 && cumLoc[u + m + 1] - cumLoc[u] <= CAPE) ++m;
        int aBatch = cumLoc[u];
        int tot = cumLoc[u + m] - aBatch;
        int descbase = N - cumLoc[u + m];

        // ---- run lengths (2/thread) + exclusive scan -> ofs (u16) ----
        int base2 = tid * 2;
        int l0 = 0, l1 = 0;
        {
            int tt = base2 >> 8, b = base2 & 255;
            if (tt < m) l0 = (int)rows[(u + tt + 1) * 256 + b] - (int)rows[(u + tt) * 256 + b];
            int i1 = base2 + 1;
            tt = i1 >> 8; b = i1 & 255;
            if (tt < m) l1 = (int)rows[(u + tt + 1) * 256 + b] - (int)rows[(u + tt) * 256 + b];
        }
        int sum2 = l0 + l1;
        int v = sum2;
        for (int off = 1; off < 64; off <<= 1) {
            int x = __shfl_up(v, off);
            if (lane >= off) v += x;
        }
        if (lane == 63) wpart[wid] = (u32)v;
        __syncthreads();
        if (tid == 0) {
            u32 run = 0;
            for (int w = 0; w < 8; ++w) { u32 tmp = wpart[w]; wpart[w] = run; run += tmp; }
        }
        __syncthreads();
        {
            int excl2 = v - sum2 + (int)wpart[wid];
            ofs[base2] = (u16)excl2;
            ofs[base2 + 1] = (u16)(excl2 + l0);
        }
        __syncthreads();

        // ---- phase A: pair-owner writes pid (tiny LDS writes) + zero event bits ----
        for (int i = tid; i < m * 256; i += 512) {
            int tt = i >> 8, b = i & 255;
            int l = (int)rows[(u + tt + 1) * 256 + b] - (int)rows[(u + tt) * 256 + b];
            int o = (int)ofs[i];
            for (int k = 0; k < l; ++k) pid[o + k] = (u16)i;
        }
        {
            int nw = (tot + 31) >> 5;
            for (int k = tid; k < nw; k += 512) bitsSh[k] = 0;
        }
        __syncthreads();

        // ---- phase B: element-parallel gather (independent 8B loads, high MLP) ----
        for (int x = tid; x < tot; x += 512) {
            int p = (int)pid[x];
            int tt = p >> 8, b = p & 255;
            int r0 = (int)rows[(u + tt) * 256 + b];
            int k = x - (int)ofs[p];
            sm[x] = S[(size_t)b * chunk + r0 + k];
        }
        __syncthreads();

        // ---- phase C: pair-parallel insertion sort of LDS-resident runs ----
        for (int i = tid; i < m * 256; i += 512) {
            int tt = i >> 8, b = i & 255;
            int l = (int)rows[(u + tt + 1) * 256 + b] - (int)rows[(u + tt) * 256 + b];
            int o = (int)ofs[i];
            for (int k = 1; k < l; ++k) {
                u64 key = sm[o + k];
                int jj = o + k - 1;
                while (jj >= o && sm[jj] > key) { sm[jj + 1] = sm[jj]; --jj; }
                sm[jj + 1] = key;
            }
        }
        __syncthreads();

        // ---- phase D: batch-wide emit (J coalesced; P run-coalesced; bits to LDS) ----
        for (int x = tid; x < tot; x += 512) {
            int lt = (int)pid[x] >> 8;                       // batch-local bin, no search
            u64 rec = sm[x];
            int i_in = x - (cumLoc[u + lt] - aBatch);
            int descpos = N - cumLoc[u + lt + 1] + i_in;
            P[descpos] = expf(__uint_as_float((u32)rec));
            J[aBatch + x] = (u32)(rec >> 33);
            if (rec & 0x100000000ull) {
                int bi = descpos - descbase;
                atomicOr(&bitsSh[bi >> 5], 1u << (bi & 31));
            }
        }
        // binhint for every 256-boundary inside this batch (global bin id)
        {
            int k0 = (aBatch + 255) >> 8;
            int k1e = cumLoc[u + m];
            for (int kk = k0 + tid; (kk << 8) < k1e; kk += 512) {
                int p = kk << 8;
                int lt = 0;
                while (p >= cumLoc[u + lt + 1]) ++lt;
                binhint[kk] = (u16)(t0 + u + lt);
            }
        }
        __syncthreads();

        // ---- flush event bits to global (edge words shared across blocks -> atomicOr) ----
        {
            int nw = (tot + 31) >> 5;
            for (int k = tid; k < nw; k += 512) {
                u32 vv = bitsSh[k];
                if (!vv) continue;
                long gb = (long)descbase + 32l * k;
                int w = (int)(gb >> 5), sh = (int)(gb & 31);
                atomicOr(&E2w[w], vv << sh);
                if (sh && (vv >> (32 - sh))) atomicOr(&E2w[w + 1], vv >> (32 - sh));
            }
        }
        __syncthreads();
        u += m;
    }
}

// ---------------- segment sums (faithful cross-indexing): keyed by dur[j], summand P[j] ----
__global__ __launch_bounds__(1024) void sums3(const int* __restrict__ dur,
                                              const float* __restrict__ P,
                                              const u32* __restrict__ E2w,
                                              float* __restrict__ expg_part,
                                              u16* __restrict__ evs_part,
                                              int N, int chunk) {
    __shared__ float he[KSEG];
    __shared__ int hv[KSEG];
    for (int i = threadIdx.x; i < KSEG; i += blockDim.x) { he[i] = 0.f; hv[i] = 0; }
    __syncthreads();
    int b = blockIdx.x;
    int s = b * chunk, e = min(N, s + chunk);
    for (int j = s + threadIdx.x; j < e; j += blockDim.x) {
        int t = dur[j];
        atomicAdd(&he[t], P[j]);
        if ((E2w[j >> 5] >> (j & 31)) & 1u) atomicAdd(&hv[t], 1);
    }
    __syncthreads();
    for (int i = threadIdx.x; i < KSEG; i += blockDim.x) {
        expg_part[(size_t)b * KSEG + i] = he[i];
        evs_part[(size_t)b * KSEG + i] = (u16)hv[i];
    }
}

__global__ void reduce_sums(const float* __restrict__ expg_part,
                            const u16* __restrict__ evs_part,
                            float* __restrict__ expg, float* __restrict__ evs, int B) {
    int t = blockIdx.x * blockDim.x + threadIdx.x;
    if (t >= KSEG) return;
    float a = 0.f;
    int v = 0;
    for (int b = 0; b < B; ++b) {
        a += expg_part[(size_t)b * KSEG + t];
        v += (int)evs_part[(size_t)b * KSEG + t];
    }
    expg[t] = a;
    evs[t] = (float)v;
}

// ---------------- risk suffix-sum + baseline hazard + total events (wave-shuffle) --------
__global__ __launch_bounds__(1024) void baseline_kernel(const float* __restrict__ expg,
                                                        const float* __restrict__ evs,
                                                        float* __restrict__ base,
                                                        float* __restrict__ ev_total, int K) {
    __shared__ float fwsum[16];
    __shared__ float carry_s;
    int tid = threadIdx.x, lane = tid & 63, wid = tid >> 6;
    if (tid == 0) carry_s = 0.f;
    float evloc = 0.f;
    __syncthreads();
    for (int b = 0; b < K; b += 1024) {
        int u = b + tid;
        int t = K - 1 - u;
        float h = 0.f, ev = 0.f;
        if (u < K) { h = expg[t]; ev = evs[t]; }
        evloc += ev;
        float v = h;
        for (int off = 1; off < 64; off <<= 1) {
            float x = __shfl_up(v, off);
            if (lane >= off) v += x;
        }
        if (lane == 63) fwsum[wid] = v;
        __syncthreads();
        if (wid == 0) {
            float wv = (lane < 16) ? fwsum[lane] : 0.f;
            for (int off = 1; off < 16; off <<= 1) {
                float x = __shfl_up(wv, off);
                if (lane >= off) wv += x;
            }
            if (lane < 16) fwsum[lane] = wv;
        }
        __syncthreads();
        float risk = v + ((wid > 0) ? fwsum[wid - 1] : 0.f) + carry_s;  // inclusive suffix
        if (u < K) base[t] = (risk > 0.f) ? ev / risk : 0.f;
        __syncthreads();
        if (tid == 1023) carry_s = risk;
    }
    // total events: wave reduce + cross-wave
    for (int off = 32; off > 0; off >>= 1) evloc += __shfl_down(evloc, off);
    __syncthreads();
    if (lane == 0) fwsum[wid] = evloc;
    __syncthreads();
    if (tid == 0) {
        float st = 0.f;
        for (int w = 0; w < 16; ++w) st += fwsum[w];
        ev_total[0] = st;
    }
}

// ---------------- MSE, flat grid-stride: (base[t(i)]*P[i] - E2bit[J[i]])^2 ----------------
__global__ __launch_bounds__(1024) void mse4(const float* __restrict__ P,
                                             const u32* __restrict__ J,
                                             const u32* __restrict__ E2w,
                                             const int* __restrict__ cum,
                                             const u16* __restrict__ binhint,
                                             const float* __restrict__ base,
                                             double* __restrict__ acc, int N) {
    int stride = gridDim.x * blockDim.x;
    double s = 0.0;
    for (int i = blockIdx.x * blockDim.x + threadIdx.x; i < N; i += stride) {
        int t = (int)binhint[i >> 8];
        while (cum[t + 1] <= i) ++t;
        u32 x = J[i];
        float ev = (float)((E2w[x >> 5] >> (x & 31)) & 1u);
        float d = base[t] * P[i] - ev;
        s += (double)d * (double)d;
    }
    __shared__ double sm[1024];
    sm[threadIdx.x] = s;
    __syncthreads();
    for (int o = 512; o > 0; o >>= 1) {
        if ((int)threadIdx.x < o) sm[threadIdx.x] += sm[threadIdx.x + o];
        __syncthreads();
    }
    if (threadIdx.x == 0) atomicAdd(acc, sm[0]);
}

__global__ void final_kernel(const double* __restrict__ acc, const float* __restrict__ ev_total,
                             float* __restrict__ out, int N) {
    out[0] = (ev_total[0] == 0.f) ? 0.0f : (float)(*acc / (double)N);
}

extern "C" void kernel_launch(void* const* d_in, const int* in_sizes, int n_in,
                              void* d_out, int out_size, void* d_ws, size_t ws_size,
                              hipStream_t stream) {
    const float* log_h = (const float*)d_in[0];
    const int* dur     = (const int*)d_in[1];
    const int* events  = (const int*)d_in[2];
    int N = in_sizes[0];
    float* out = (float*)d_out;

    char* ws = (char*)d_ws;
    size_t off = 0;
    auto alloc = [&](size_t bytes) -> char* {
        char* p = ws + off;
        off = (off + bytes + 255) & ~(size_t)255;
        return p;
    };
    double* acc  = (double*)alloc(8);
    u32*    E2w  = (u32*)alloc(((size_t)N / 32 + 2) * 4);   // event bitfield (desc-indexed)
    size_t zero_bytes = off;                                 // acc + E2w must start at 0
    float*  ev_total = (float*)alloc(4);
    int*    cum      = (int*)alloc((KSEG + 1) * 4);
    float*  expg     = (float*)alloc(KSEG * 4);
    float*  evs      = (float*)alloc(KSEG * 4);
    float*  base     = (float*)alloc(KSEG * 4);
    u16*    binhint  = (u16*)alloc(((size_t)N / 256 + 1) * 2);
    u16*    Pb       = (u16*)alloc((size_t)NBLK * (KSEG + 1) * 2);
    u16*    PbT      = (u16*)alloc((size_t)(KSEG + 1) * NBLK * 2);
    u64*    S        = (u64*)alloc((size_t)N * 8);
    float*  P        = (float*)alloc((size_t)N * 4);
    u32*    J        = (u32*)alloc((size_t)N * 4);
    (void)ws_size;

    // sums partials alias S (dead after runsort_ep; mse4 uses P/J, not S)
    float* expg_part = (float*)S;
    u16*   evs_part  = (u16*)((char*)S + (size_t)NBLK * KSEG * 4 + 256);

    int chunk = (N + NBLK - 1) / NBLK;   // 31250 < 65536 -> u16 offsets valid; <= RECN

    hipMemsetAsync(d_ws, 0, zero_bytes, stream);

    localsort_lds<<<NBLK, 1024, 0, stream>>>(dur, log_h, events, S, Pb, N, chunk);
    transpose_pb<<<dim3((KSEG + 64) / 64, NBLK / 64), dim3(64, 4), 0, stream>>>(Pb, PbT);
    cum_rows<<<(KSEG + 4) / 4, 256, 0, stream>>>(PbT, cum);
    runsort_ep<<<(KSEG + GBIN - 1) / GBIN, 512, 0, stream>>>(S, cum, PbT, P, J, E2w,
                                                             binhint, N, chunk);
    sums3<<<NBLK, 1024, 0, stream>>>(dur, P, E2w, expg_part, evs_part, N, chunk);
    reduce_sums<<<(KSEG + 255) / 256, 256, 0, stream>>>(expg_part, evs_part, expg, evs, NBLK);
    baseline_kernel<<<1, 1024, 0, stream>>>(expg, evs, base, ev_total, KSEG);
    mse4<<<512, 1024, 0, stream>>>(P, J, E2w, cum, binhint, base, acc, N);
    final_kernel<<<1, 1, 0, stream>>>(acc, ev_total, out, N);
}